// Round 1
// baseline (131.023 us; speedup 1.0000x reference)
//
#include <hip/hip_runtime.h>

// db4 decomposition filters, ascending order (pywt). child(t) = sum_j DEC[j]*parent(2t+1-j).
__device__ __constant__ float LOF[8] = {
    -0.010597401784997278f,  0.032883011666982945f,  0.030841381835986965f,
    -0.18703481171888114f,  -0.02798376941698385f,   0.6308807679295904f,
     0.7148465705525415f,    0.23037781330885523f};
__device__ __constant__ float HIF[8] = {
    -0.23037781330885523f,   0.7148465705525415f,   -0.6308807679295904f,
    -0.02798376941698385f,   0.18703481171888114f,   0.030841381835986965f,
     0.032883011666982945f, -0.010597401784997278f};

// One analysis level for all 1024 (b,f) signals. Thread = (b, t, f4), f4 in [0,32).
// Strides are in float4 units. Both lo and hi computed from the same 8 loads.
__global__ void dwt_level_kernel(const float4* __restrict__ in,
                                 float4* __restrict__ out_lo,
                                 float4* __restrict__ out_hi,
                                 int Sin, int Sout, int in_bs, int lo_bs, int hi_bs) {
    int idx = blockIdx.x * 256 + threadIdx.x;
    int total = 8 * Sout * 32;
    if (idx >= total) return;
    int f    = idx & 31;
    int rest = idx >> 5;
    int t    = rest % Sout;
    int b    = rest / Sout;
    const float4* ib = in + b * in_bs + f;
    float4 lo = {0.f, 0.f, 0.f, 0.f};
    float4 hi = {0.f, 0.f, 0.f, 0.f};
    int s0 = 2 * t + 1;
#pragma unroll
    for (int j = 0; j < 8; ++j) {
        int s = s0 - j;
        if (s >= 0 && s < Sin) {
            float4 v = ib[s * 32];
            float cl = LOF[j], ch = HIF[j];
            lo.x = fmaf(cl, v.x, lo.x); lo.y = fmaf(cl, v.y, lo.y);
            lo.z = fmaf(cl, v.z, lo.z); lo.w = fmaf(cl, v.w, lo.w);
            hi.x = fmaf(ch, v.x, hi.x); hi.y = fmaf(ch, v.y, hi.y);
            hi.z = fmaf(ch, v.z, hi.z); hi.w = fmaf(ch, v.w, hi.w);
        }
    }
    out_lo[b * lo_bs + t * 32 + f] = lo;
    out_hi[b * hi_bs + t * 32 + f] = hi;
}

// Final assembly: zero-fill tails of c0..c3, c4 = c1+c2+c3 (placed), c5 = c0.
// Thread = (b, s, f4). Coefficient regions of c0..c3 were written by the level kernels.
__global__ void assemble_kernel(float4* __restrict__ out) {
    int idx = blockIdx.x * 256 + threadIdx.x;  // total 8*4096*32 = 1048576, exact
    int f    = idx & 31;
    int rest = idx >> 5;          // b*4096 + s
    int s    = rest & 4095;
    long base = (long)rest * 32 + f;
    const long CH = 8L * 4096 * 32;  // channel stride in float4
    float4 z = {0.f, 0.f, 0.f, 0.f};
    float4 v0, v1, v2, v3;
    if (s < 518)  { v0 = out[base]; }          else { v0 = z; out[base] = z; }
    if (s < 2051) { v1 = out[CH + base]; }     else { v1 = z; out[CH + base] = z; }
    if (s < 1029) { v2 = out[2 * CH + base]; } else { v2 = z; out[2 * CH + base] = z; }
    if (s < 518)  { v3 = out[3 * CH + base]; } else { v3 = z; out[3 * CH + base] = z; }
    float4 hsum;
    hsum.x = v1.x + v2.x + v3.x;
    hsum.y = v1.y + v2.y + v3.y;
    hsum.z = v1.z + v2.z + v3.z;
    hsum.w = v1.w + v2.w + v3.w;
    out[4 * CH + base] = hsum;
    out[5 * CH + base] = v0;
}

extern "C" void kernel_launch(void* const* d_in, const int* in_sizes, int n_in,
                              void* d_out, int out_size, void* d_ws, size_t ws_size,
                              hipStream_t stream) {
    const float4* x   = (const float4*)d_in[0];   // [8, 4096, 128] f32
    float4*       out = (float4*)d_out;           // [6, 8, 4096, 128] f32
    // Workspace: lo1 [8,2051,128] then lo2 [8,1029,128]  (12.6 MB of d_ws)
    float4* lo1 = (float4*)d_ws;
    float4* lo2 = lo1 + 8 * 2051 * 32;

    const long CH = 8L * 4096 * 32;
    float4* c0 = out;            // approx  (lo3 placed)
    float4* c1 = out + CH;       // d1 = hi1
    float4* c2 = out + 2 * CH;   // d2 = hi2
    float4* c3 = out + 3 * CH;   // d3 = hi3

    // Level 1: x(4096) -> lo1(2051) in ws, hi1(2051) placed into c1
    {
        int total = 8 * 2051 * 32;
        dwt_level_kernel<<<(total + 255) / 256, 256, 0, stream>>>(
            x, lo1, c1, 4096, 2051, 4096 * 32, 2051 * 32, 4096 * 32);
    }
    // Level 2: lo1(2051) -> lo2(1029) in ws, hi2(1029) placed into c2
    {
        int total = 8 * 1029 * 32;
        dwt_level_kernel<<<(total + 255) / 256, 256, 0, stream>>>(
            lo1, lo2, c2, 2051, 1029, 2051 * 32, 1029 * 32, 4096 * 32);
    }
    // Level 3: lo2(1029) -> lo3(518) placed into c0, hi3(518) placed into c3
    {
        int total = 8 * 518 * 32;
        dwt_level_kernel<<<(total + 255) / 256, 256, 0, stream>>>(
            lo2, c0, c3, 1029, 518, 1029 * 32, 4096 * 32, 4096 * 32);
    }
    // Assembly: zero tails, c4 = c1+c2+c3, c5 = c0
    assemble_kernel<<<4096, 256, 0, stream>>>(out);
}